// Round 8
// baseline (271.792 us; speedup 1.0000x reference)
//
#include <hip/hip_runtime.h>

// Problem constants (fixed by setup_inputs)
#define DIM 512
#define NQ 64
#define BATCH 2048

typedef __bf16  bf16x8  __attribute__((ext_vector_type(8)));
typedef float   floatx4 __attribute__((ext_vector_type(4)));

static __device__ inline unsigned short f2bf(float f) {
    unsigned int u = __float_as_uint(f);
    return (unsigned short)((u + 0x7fffu + ((u >> 16) & 1u)) >> 16);  // RNE
}
static __device__ inline float bf2f(unsigned short h) {
    return __uint_as_float((unsigned int)h << 16);
}
static __device__ inline unsigned int pack2(float a, float b) {
    return (unsigned)f2bf(a) | ((unsigned)f2bf(b) << 16);
}

// Fused pack+expand v5 (proven: cut non-GEMM residual 86 -> 61 us). Grid (512,5):
//   y = 0..3 : expand q_coefs -> W[k][e][d] + npart partials (float4 loads,
//              in-register 4x4 k<->d transpose via shfl_xor)
//   y = 4    : pack points fp32 -> bf16 Pb
__global__ __launch_bounds__(512, 3)
void hsq_expand_kernel(const float* __restrict__ qc,
                       const float* __restrict__ pts,
                       unsigned short* __restrict__ W,
                       unsigned short* __restrict__ Pb,
                       float* __restrict__ npart) {
    const int e = blockIdx.x;             // 0..511

    if (blockIdx.y == 4) {
        const int i4 = e * 512 + threadIdx.x;
        const float4 v = *(const float4*)(pts + (size_t)i4 * 4);
        uint2 wv;
        wv.x = pack2(v.x, v.y); wv.y = pack2(v.z, v.w);
        *(uint2*)(Pb + (size_t)i4 * 4) = wv;
        return;
    }

    const int dblk = blockIdx.y;          // 0..3
    const int pb   = dblk * 512 + e;      // 0..2047
    const int tid  = threadIdx.x;
    const int w    = tid >> 6;            // 0..7
    const int lane = tid & 63;
    const int g    = lane >> 4;           // row-slot 0..3 (pre-transpose)
    const int u    = lane & 15;           // k-quad 0..15
    const int d0   = dblk * 128;

    __shared__ unsigned short tv[64 * 136];   // [k][136] (16B-aligned rows)
    __shared__ float part2[8][64];

    float4 nacc4 = {0.f, 0.f, 0.f, 0.f};

#pragma unroll
    for (int p = 0; p < 4; ++p) {
        const int rloc = p * 32 + w * 4;  // wave's 4-row base this pass
        const int d = d0 + rloc + g;      // this lane's row (pre-transpose)
        const int i = d < e ? d : e;
        const int j = d < e ? e : d;
        const int idx = i * DIM - ((i * (i - 1)) >> 1) + (j - i);
        float4 f = *(const float4*)(qc + (size_t)idx * NQ + u * 4);

        if (d >= e) {
            nacc4.x += f.x * f.x; nacc4.y += f.y * f.y;
            nacc4.z += f.z * f.z; nacc4.w += f.w * f.w;
        }
        const float s = (d == e) ? 2.0f : 1.41421356237309515f;
        float4 v = {f.x * s, f.y * s, f.z * s, f.w * s};

        // 4x4 transpose across quartet lanes {u, u+16, u+32, u+48}
        {
            float s0 = (g & 2) ? v.x : v.z;
            float s1 = (g & 2) ? v.y : v.w;
            const float r0 = __shfl_xor(s0, 32);
            const float r1 = __shfl_xor(s1, 32);
            if (g & 2) { v.x = r0; v.y = r1; } else { v.z = r0; v.w = r1; }
        }
        {
            float s0 = (g & 1) ? v.x : v.y;
            float s1 = (g & 1) ? v.z : v.w;
            const float r0 = __shfl_xor(s0, 16);
            const float r1 = __shfl_xor(s1, 16);
            if (g & 1) { v.x = r0; v.z = r1; } else { v.y = r0; v.w = r1; }
        }
        const int k = u * 4 + g;
        uint2 wv;
        wv.x = pack2(v.x, v.y);
        wv.y = pack2(v.z, v.w);
        *(uint2*)&tv[k * 136 + rloc] = wv;
    }

    nacc4.x += __shfl_xor(nacc4.x, 16); nacc4.y += __shfl_xor(nacc4.y, 16);
    nacc4.z += __shfl_xor(nacc4.z, 16); nacc4.w += __shfl_xor(nacc4.w, 16);
    nacc4.x += __shfl_xor(nacc4.x, 32); nacc4.y += __shfl_xor(nacc4.y, 32);
    nacc4.z += __shfl_xor(nacc4.z, 32); nacc4.w += __shfl_xor(nacc4.w, 32);
    if (g == 0) *(float4*)&part2[w][u * 4] = nacc4;
    __syncthreads();

#pragma unroll
    for (int r = 0; r < 2; ++r) {
        const int kk = r * 32 + (tid >> 4);
        const int uu = tid & 15;
        const uint4 ww = *(const uint4*)&tv[kk * 136 + uu * 8];
        *(uint4*)(W + ((size_t)(kk * DIM + e)) * DIM + dblk * 128 + uu * 8) = ww;
    }
    if (tid < 64) {
        npart[(size_t)tid * 2048 + pb] =
            part2[0][tid] + part2[1][tid] + part2[2][tid] + part2[3][tid] +
            part2[4][tid] + part2[5][tid] + part2[6][tid] + part2[7][tid];
    }
}

// ---------------------------------------------------------------------------
// GEMM v7b (v7 with two fixes). BM=BN=256, BK=64, 8 waves, per-wave 128x64.
//  FIX 1 (correctness): B k-half frag offsets are 64-BYTE halves of the
//    128-byte row (R1's proven 0*64/1*64), not 32 -- v7's 1*32 read a region
//    straddling both halves with broken swizzle (absmax 0.38).
//  FIX 2 (pipeline): issue order per K-tile is now
//    bfr(8 ds_read) -> afr kh0 (8 vmem) -> STAGE_B next (4 vmem) ->
//    MFMA kh0 -> afr kh1 (8 vmem) -> MFMA kh1 -> vmcnt(0) -> barrier.
//    v7 issued the stage FIRST, so the compiler's in-order vmcnt wait for the
//    A-frags drained the stage too (no prefetch overlap). Now the stage rides
//    across the kh0 MFMA block.
// Structure under test (unchanged from v7's intent): A read directly from
// L2-hot Pb (no LDS staging), LDS = 2 x 32 KB B buffers only, ONE barrier per
// K-tile (8 total vs R1's 64).
// ---------------------------------------------------------------------------
__global__ __launch_bounds__(512, 2)
void hsq_gemm_kernel(const unsigned short* __restrict__ Pb,
                     const unsigned short* __restrict__ W,
                     const float* __restrict__ l_coefs,
                     float2* __restrict__ part) {
    extern __shared__ unsigned short smem[];

    // bijective XCD swizzle (1024 % 8 == 0): consecutive wg on one XCD share k
    const int bid = blockIdx.x;
    const int wg  = (bid & 7) * 128 + (bid >> 3);
    const int k   = wg >> 4;              // 0..63
    const int rem = wg & 15;
    const int et  = rem >> 3;             // 0..1  (e-tile of 256)
    const int mt  = rem & 7;              // 0..7  (batch tile of 256)
    const int m0  = mt * 256;

    const int tid  = threadIdx.x;
    const int lane = tid & 63;
    const int w    = tid >> 6;            // 0..7
    const int wm   = w >> 2;              // 0..1 (M half of 128)
    const int wn   = w & 3;               // 0..3 (N group of 64)
    const int c    = lane & 15;
    const int quad = lane >> 4;

    const unsigned short* Wk = W + ((size_t)k * DIM + (size_t)et * 256) * DIM;

    // B staging source (linear LDS dest; source carries the swizzle involution)
    const int scolb = ((tid & 7) * 16) ^ (((tid >> 3) & 7) << 4);   // bytes
    const unsigned short* pBs = Wk + (size_t)(tid >> 3) * DIM + (scolb >> 1);

    // A direct-load base: row = m0 + wm*128 + mi*16 + c, k = T*64 + kh*32 + quad*8
    const unsigned short* pA = Pb + (size_t)(m0 + wm * 128 + c) * DIM + quad * 8;

    // B frag read offsets (elements); row&7 == c&7 for every frag row.
    // k-halves are 64-BYTE halves of the 128-byte row (FIX 1).
    const int koff0 = ((0 * 64 + quad * 16) ^ ((c & 7) << 4)) >> 1;
    const int koff1 = ((1 * 64 + quad * 16) ^ ((c & 7) << 4)) >> 1;
    const int bwoff = (wn * 64 + c) * 64;   // e-row (wn*64 + ni*16 + c) base

// stage full B tile (256 rows x 64 k) for K-tile T into buffer BUF (4 instrs)
#define STAGE_B(BUF, T) do {                                                   \
    const unsigned short* src_ = pBs + (size_t)(T) * 64;                       \
    _Pragma("unroll")                                                          \
    for (int cc_ = 0; cc_ < 4; ++cc_) {                                        \
        __builtin_amdgcn_global_load_lds(                                      \
            (const __attribute__((address_space(1))) unsigned int*)            \
                (src_ + (size_t)(cc_ * 64) * DIM),                             \
            (__attribute__((address_space(3))) unsigned int*)                  \
                (smem + (BUF) * 16384 + cc_ * 4096 + tid * 8),                 \
            16, 0, 0);                                                         \
    }                                                                          \
} while (0)

#define KTILE(BUF, T, DO_STAGE) do {                                           \
    bf16x8 bfr[4][2];                                                          \
    _Pragma("unroll")                                                          \
    for (int ni_ = 0; ni_ < 4; ++ni_) {                                        \
        bfr[ni_][0] = *(const bf16x8*)(smem + (BUF) * 16384 + bwoff + ni_ * 1024 + koff0); \
        bfr[ni_][1] = *(const bf16x8*)(smem + (BUF) * 16384 + bwoff + ni_ * 1024 + koff1); \
    }                                                                          \
    bf16x8 afr[8];                                                             \
    _Pragma("unroll")                                                          \
    for (int mi_ = 0; mi_ < 8; ++mi_)                                          \
        afr[mi_] = *(const bf16x8*)(pA + (size_t)mi_ * 16 * DIM + (T) * 64);   \
    asm volatile("" ::: "memory");                                             \
    DO_STAGE;                                                                  \
    asm volatile("" ::: "memory");                                             \
    __builtin_amdgcn_s_setprio(1);                                             \
    _Pragma("unroll")                                                          \
    for (int mi_ = 0; mi_ < 8; ++mi_)                                          \
        _Pragma("unroll")                                                      \
        for (int ni_ = 0; ni_ < 4; ++ni_)                                      \
            acc[mi_][ni_] = __builtin_amdgcn_mfma_f32_16x16x32_bf16(           \
                afr[mi_], bfr[ni_][0], acc[mi_][ni_], 0, 0, 0);                \
    __builtin_amdgcn_s_setprio(0);                                             \
    _Pragma("unroll")                                                          \
    for (int mi_ = 0; mi_ < 8; ++mi_)                                          \
        afr[mi_] = *(const bf16x8*)(pA + (size_t)mi_ * 16 * DIM + (T) * 64 + 32); \
    __builtin_amdgcn_s_setprio(1);                                             \
    _Pragma("unroll")                                                          \
    for (int mi_ = 0; mi_ < 8; ++mi_)                                          \
        _Pragma("unroll")                                                      \
        for (int ni_ = 0; ni_ < 4; ++ni_)                                      \
            acc[mi_][ni_] = __builtin_amdgcn_mfma_f32_16x16x32_bf16(           \
                afr[mi_], bfr[ni_][1], acc[mi_][ni_], 0, 0, 0);                \
    __builtin_amdgcn_s_setprio(0);                                             \
    asm volatile("s_waitcnt vmcnt(0)" ::: "memory");                           \
    __builtin_amdgcn_s_barrier();                                              \
    asm volatile("" ::: "memory");                                             \
} while (0)

    floatx4 acc[8][4];
#pragma unroll
    for (int mi = 0; mi < 8; ++mi)
#pragma unroll
        for (int ni = 0; ni < 4; ++ni)
            acc[mi][ni] = (floatx4){0.f, 0.f, 0.f, 0.f};

    // prologue: stage B(0) into buf0, drain, barrier
    STAGE_B(0, 0);
    asm volatile("s_waitcnt vmcnt(0)" ::: "memory");
    __builtin_amdgcn_s_barrier();
    asm volatile("" ::: "memory");

#pragma unroll 1
    for (int it = 0; it < 4; ++it) {
        KTILE(0, 2 * it,     { if (true)   STAGE_B(1, 2 * it + 1); });
        KTILE(1, 2 * it + 1, { if (it < 3) STAGE_B(0, 2 * it + 2); });
    }
#undef KTILE
#undef STAGE_B

    __syncthreads();

    // ---- Epilogue: pv = sum_e p*(0.5g+l), pg = sum_e (g+l)^2 over this et ----
    float lcv[4];
#pragma unroll
    for (int ni = 0; ni < 4; ++ni)
        lcv[ni] = l_coefs[(et * 256 + wn * 64 + ni * 16 + c) * NQ + k];

    const unsigned short* Pe = Pb + (size_t)(m0 + wm * 128) * DIM + et * 256 + wn * 64 + c;
    float* red = (float*)smem;   // reuse LDS: 8 waves x 128 rows x {pv,pg} = 8 KB

#pragma unroll
    for (int mi = 0; mi < 8; ++mi)
#pragma unroll
        for (int r = 0; r < 4; ++r) {
            const unsigned short* Prow = Pe + (size_t)(mi * 16 + quad * 4 + r) * DIM;
            float pv = 0.f, pg = 0.f;
#pragma unroll
            for (int ni = 0; ni < 4; ++ni) {
                const float g = acc[mi][ni][r];
                const float l = lcv[ni];
                pv += bf2f(Prow[ni * 16]) * (0.5f * g + l);
                const float gq = g + l;
                pg += gq * gq;
            }
#pragma unroll
            for (int off = 1; off < 16; off <<= 1) {
                pv += __shfl_xor(pv, off);
                pg += __shfl_xor(pg, off);
            }
            if (c == 0) {
                const int row16 = mi * 16 + quad * 4 + r;
                red[(w * 128 + row16) * 2 + 0] = pv;
                red[(w * 128 + row16) * 2 + 1] = pg;
            }
        }
    __syncthreads();

    if (tid < 256) {
        const int row16 = tid & 127;
        const int wmf   = tid >> 7;
        float pv = 0.f, pg = 0.f;
#pragma unroll
        for (int wnf = 0; wnf < 4; ++wnf) {
            const int wi = wmf * 4 + wnf;
            pv += red[(wi * 128 + row16) * 2 + 0];
            pg += red[(wi * 128 + row16) * 2 + 1];
        }
        part[((size_t)(et * NQ + k)) * BATCH + m0 + wmf * 128 + row16] =
            make_float2(pv, pg);
    }
}

// Final: block per k. Reduces npart[k][*] -> norm2 in-block, then combines the
// 2 e-range partials into scores (coalesced reads).
__global__ void hsq_final_kernel(const float2* __restrict__ part,
                                 const float* __restrict__ npart,
                                 const float* __restrict__ free_coefs,
                                 float* __restrict__ out) {
    const int k = blockIdx.x;
    const int t = threadIdx.x;
    __shared__ float ws[4];

    const float4* src = (const float4*)(npart + (size_t)k * 2048);
    const float4 a = src[t * 2], b = src[t * 2 + 1];
    float s = a.x + a.y + a.z + a.w + b.x + b.y + b.z + b.w;
#pragma unroll
    for (int off = 1; off < 64; off <<= 1) s += __shfl_xor(s, off);
    if ((t & 63) == 0) ws[t >> 6] = s;
    __syncthreads();
    const float nrm = sqrtf(ws[0] + ws[1] + ws[2] + ws[3]);
    const float fc  = free_coefs[k];

#pragma unroll
    for (int i = 0; i < 8; ++i) {
        const int bidx = i * 256 + t;
        float pv = 0.f, pg = 0.f;
#pragma unroll
        for (int eb = 0; eb < 2; ++eb) {
            const float2 p = part[((size_t)(eb * NQ + k)) * BATCH + bidx];
            pv += p.x; pg += p.y;
        }
        const float vals = fabsf(pv + fc);
        out[(size_t)bidx * NQ + k] = (sqrtf(0.25f * pg + vals * nrm) - 0.5f * sqrtf(pg)) / nrm;
    }
}

extern "C" void kernel_launch(void* const* d_in, const int* in_sizes, int n_in,
                              void* d_out, int out_size, void* d_ws, size_t ws_size,
                              hipStream_t stream) {
    const float* points     = (const float*)d_in[0];  // (2048, 512)
    const float* q_coefs    = (const float*)d_in[1];  // (131328, 64)
    const float* l_coefs    = (const float*)d_in[2];  // (512, 64)
    const float* free_coefs = (const float*)d_in[3];  // (1, 64)
    float* out = (float*)d_out;                       // (2048, 64)

    char* ws = (char*)d_ws;
    unsigned short* W  = (unsigned short*)ws;                              // 32 MiB
    unsigned short* Pb = (unsigned short*)(ws + 33554432);                 // 2 MiB
    float2*         part  = (float2*)(ws + 35651584);                      // 2 MiB
    float*          npart = (float*)(ws + 37748736);                       // 512 KiB

    // 64 KiB dynamic LDS (one-time opt-in; not a stream op, graph-safe).
    static bool attr_done = false;
    if (!attr_done) {
        (void)hipFuncSetAttribute((const void*)hsq_gemm_kernel,
                                  hipFuncAttributeMaxDynamicSharedMemorySize,
                                  65536);
        attr_done = true;
    }

    hsq_expand_kernel<<<dim3(512, 5), 512, 0, stream>>>(q_coefs, points, W, Pb, npart);
    hsq_gemm_kernel<<<dim3(1024), dim3(512), 65536, stream>>>(Pb, W, l_coefs, part);
    hsq_final_kernel<<<dim3(NQ), 256, 0, stream>>>(part, npart, free_coefs, out);
}

// Round 9
// 193.386 us; speedup vs baseline: 1.4054x; 1.4054x over previous
//
#include <hip/hip_runtime.h>

// Problem constants (fixed by setup_inputs)
#define DIM 512
#define NQ 64
#define BATCH 2048

typedef __bf16  bf16x8  __attribute__((ext_vector_type(8)));
typedef float   floatx4 __attribute__((ext_vector_type(4)));

static __device__ inline unsigned short f2bf(float f) {
    unsigned int u = __float_as_uint(f);
    return (unsigned short)((u + 0x7fffu + ((u >> 16) & 1u)) >> 16);  // RNE
}
static __device__ inline float bf2f(unsigned short h) {
    return __uint_as_float((unsigned int)h << 16);
}
static __device__ inline unsigned int pack2(float a, float b) {
    return (unsigned)f2bf(a) | ((unsigned)f2bf(b) << 16);
}

// Fused pack+expand v5 (proven: cut non-GEMM residual ~86 -> ~52-61 us
// session-adjusted). Grid (512, 5):
//   y = 0..3 : expand q_coefs -> W[k][e][d] + npart partials (float4 loads,
//              in-register 4x4 k<->d transpose via shfl_xor)
//   y = 4    : pack points fp32 -> bf16 Pb
__global__ __launch_bounds__(512, 3)
void hsq_expand_kernel(const float* __restrict__ qc,
                       const float* __restrict__ pts,
                       unsigned short* __restrict__ W,
                       unsigned short* __restrict__ Pb,
                       float* __restrict__ npart) {
    const int e = blockIdx.x;             // 0..511

    if (blockIdx.y == 4) {
        const int i4 = e * 512 + threadIdx.x;
        const float4 v = *(const float4*)(pts + (size_t)i4 * 4);
        uint2 wv;
        wv.x = pack2(v.x, v.y); wv.y = pack2(v.z, v.w);
        *(uint2*)(Pb + (size_t)i4 * 4) = wv;
        return;
    }

    const int dblk = blockIdx.y;          // 0..3
    const int pb   = dblk * 512 + e;      // 0..2047
    const int tid  = threadIdx.x;
    const int w    = tid >> 6;            // 0..7
    const int lane = tid & 63;
    const int g    = lane >> 4;           // row-slot 0..3 (pre-transpose)
    const int u    = lane & 15;           // k-quad 0..15
    const int d0   = dblk * 128;

    __shared__ unsigned short tv[64 * 136];   // [k][136] (16B-aligned rows)
    __shared__ float part2[8][64];

    float4 nacc4 = {0.f, 0.f, 0.f, 0.f};

#pragma unroll
    for (int p = 0; p < 4; ++p) {
        const int rloc = p * 32 + w * 4;  // wave's 4-row base this pass
        const int d = d0 + rloc + g;      // this lane's row (pre-transpose)
        const int i = d < e ? d : e;
        const int j = d < e ? e : d;
        const int idx = i * DIM - ((i * (i - 1)) >> 1) + (j - i);
        float4 f = *(const float4*)(qc + (size_t)idx * NQ + u * 4);

        if (d >= e) {
            nacc4.x += f.x * f.x; nacc4.y += f.y * f.y;
            nacc4.z += f.z * f.z; nacc4.w += f.w * f.w;
        }
        const float s = (d == e) ? 2.0f : 1.41421356237309515f;
        float4 v = {f.x * s, f.y * s, f.z * s, f.w * s};

        // 4x4 transpose across quartet lanes {u, u+16, u+32, u+48}
        {
            float s0 = (g & 2) ? v.x : v.z;
            float s1 = (g & 2) ? v.y : v.w;
            const float r0 = __shfl_xor(s0, 32);
            const float r1 = __shfl_xor(s1, 32);
            if (g & 2) { v.x = r0; v.y = r1; } else { v.z = r0; v.w = r1; }
        }
        {
            float s0 = (g & 1) ? v.x : v.y;
            float s1 = (g & 1) ? v.z : v.w;
            const float r0 = __shfl_xor(s0, 16);
            const float r1 = __shfl_xor(s1, 16);
            if (g & 1) { v.x = r0; v.z = r1; } else { v.y = r0; v.w = r1; }
        }
        const int k = u * 4 + g;
        uint2 wv;
        wv.x = pack2(v.x, v.y);
        wv.y = pack2(v.z, v.w);
        *(uint2*)&tv[k * 136 + rloc] = wv;
    }

    nacc4.x += __shfl_xor(nacc4.x, 16); nacc4.y += __shfl_xor(nacc4.y, 16);
    nacc4.z += __shfl_xor(nacc4.z, 16); nacc4.w += __shfl_xor(nacc4.w, 16);
    nacc4.x += __shfl_xor(nacc4.x, 32); nacc4.y += __shfl_xor(nacc4.y, 32);
    nacc4.z += __shfl_xor(nacc4.z, 32); nacc4.w += __shfl_xor(nacc4.w, 32);
    if (g == 0) *(float4*)&part2[w][u * 4] = nacc4;
    __syncthreads();

#pragma unroll
    for (int r = 0; r < 2; ++r) {
        const int kk = r * 32 + (tid >> 4);
        const int uu = tid & 15;
        const uint4 ww = *(const uint4*)&tv[kk * 136 + uu * 8];
        *(uint4*)(W + ((size_t)(kk * DIM + e)) * DIM + dblk * 128 + uu * 8) = ww;
    }
    if (tid < 64) {
        npart[(size_t)tid * 2048 + pb] =
            part2[0][tid] + part2[1][tid] + part2[2][tid] + part2[3][tid] +
            part2[4][tid] + part2[5][tid] + part2[6][tid] + part2[7][tid];
    }
}

// ---------------------------------------------------------------------------
// 256x256 8-phase GEMM -- FROZEN R1/R3 version (105.1/104.8 us @ R3-session
// clocks, MfmaUtil ~27, FETCH ~25 MB, twice-reproduced). Structural model
// (explains the 27% pin across R1/R3/R4): per K-tile the block reads 192 KB
// of fragments from LDS (~2300 cyc at 85 B/cyc) vs ~610 cyc of MFMA work --
// the LDS pipe is ~3.75x oversubscribed vs the matrix pipe; 614/2304 = 27%.
// Fragment traffic is fixed by the 128x64/wave register tile; all larger
// tiles spill (R6: 111 MB scratch). A-direct-from-L2 (R8) and 16-wave (R6)
// both regressed. This kernel is at its decomposition's structural limit.
// ---------------------------------------------------------------------------
__global__ __launch_bounds__(512, 2)
void hsq_gemm_kernel(const unsigned short* __restrict__ Pb,
                     const unsigned short* __restrict__ W,
                     const float* __restrict__ l_coefs,
                     float2* __restrict__ part) {
    extern __shared__ unsigned short smem[];

    // bijective XCD swizzle (1024 % 8 == 0): consecutive wg on one XCD share k
    const int bid = blockIdx.x;
    const int wg  = (bid & 7) * 128 + (bid >> 3);
    const int k   = wg >> 4;              // 0..63
    const int rem = wg & 15;
    const int et  = rem >> 3;             // 0..1  (e-tile of 256)
    const int mt  = rem & 7;              // 0..7  (batch tile of 256)
    const int m0  = mt * 256;

    const int tid  = threadIdx.x;
    const int lane = tid & 63;
    const int w    = tid >> 6;            // 0..7
    const int wm   = w >> 2;              // 0..1
    const int wn   = w & 3;               // 0..3
    const int c    = lane & 15;
    const int quad = lane >> 4;

    const unsigned short* Wk = W + ((size_t)k * DIM + (size_t)et * 256) * DIM;

    // staging source (linear LDS dest; source carries the swizzle)
    const int scolb = ((tid & 7) * 16) ^ (((tid >> 3) & 7) << 4);   // bytes
    const unsigned short* pAs = Pb + (size_t)(m0 + (tid >> 3)) * DIM + (scolb >> 1);
    const unsigned short* pBs = Wk + (size_t)(tid >> 3) * DIM + (scolb >> 1);

    // frag read offsets (elements); row&7 == c&7 for every frag row
    const int xorv  = (c & 7) << 4;                              // bytes
    const int koff0 = ((0 * 64 + quad * 16) ^ xorv) >> 1;
    const int koff1 = ((1 * 64 + quad * 16) ^ xorv) >> 1;
    const int awoff = wm * 8192 + c * 64;
    const int bwoff = (wn >> 1) * 8192 + (wn & 1) * 4096 + c * 64;

#define STAGE_HALF(LDSELEM, GSRC) do {                                         \
    _Pragma("unroll")                                                          \
    for (int cc_ = 0; cc_ < 2; ++cc_) {                                        \
        __builtin_amdgcn_global_load_lds(                                      \
            (const __attribute__((address_space(1))) unsigned int*)            \
                ((GSRC) + (size_t)(cc_ * 64) * DIM),                           \
            (__attribute__((address_space(3))) unsigned int*)                  \
                (smem + (LDSELEM) + cc_ * 4096 + tid * 8),                     \
            16, 0, 0);                                                         \
    }                                                                          \
} while (0)

#define LOADB(BBASE) do {                                                      \
    _Pragma("unroll")                                                          \
    for (int ni_ = 0; ni_ < 4; ++ni_) {                                        \
        bfr[ni_][0] = *(const bf16x8*)(smem + (BBASE) + bwoff + ni_ * 1024 + koff0); \
        bfr[ni_][1] = *(const bf16x8*)(smem + (BBASE) + bwoff + ni_ * 1024 + koff1); \
    }                                                                          \
} while (0)

#define PHASE(ABASE, MI0, PRE_B, STAGE_AND_WAIT) do {                          \
    bf16x8 a00 = *(const bf16x8*)(smem + (ABASE) + awoff + (MI0) * 1024 + koff0);     \
    bf16x8 a01 = *(const bf16x8*)(smem + (ABASE) + awoff + (MI0) * 1024 + koff1);     \
    bf16x8 a10 = *(const bf16x8*)(smem + (ABASE) + awoff + ((MI0) + 1) * 1024 + koff0); \
    bf16x8 a11 = *(const bf16x8*)(smem + (ABASE) + awoff + ((MI0) + 1) * 1024 + koff1); \
    PRE_B;                                                                     \
    STAGE_AND_WAIT;                                                            \
    asm volatile("" ::: "memory");                                             \
    __builtin_amdgcn_s_barrier();                                              \
    asm volatile("" ::: "memory");                                             \
    __builtin_amdgcn_s_setprio(1);                                             \
    _Pragma("unroll")                                                          \
    for (int ni_ = 0; ni_ < 4; ++ni_) {                                        \
        acc[(MI0)][ni_]     = __builtin_amdgcn_mfma_f32_16x16x32_bf16(a00, bfr[ni_][0], acc[(MI0)][ni_], 0, 0, 0);     \
        acc[(MI0)][ni_]     = __builtin_amdgcn_mfma_f32_16x16x32_bf16(a01, bfr[ni_][1], acc[(MI0)][ni_], 0, 0, 0);     \
        acc[(MI0) + 1][ni_] = __builtin_amdgcn_mfma_f32_16x16x32_bf16(a10, bfr[ni_][0], acc[(MI0) + 1][ni_], 0, 0, 0); \
        acc[(MI0) + 1][ni_] = __builtin_amdgcn_mfma_f32_16x16x32_bf16(a11, bfr[ni_][1], acc[(MI0) + 1][ni_], 0, 0, 0); \
    }                                                                          \
    __builtin_amdgcn_s_setprio(0);                                             \
    asm volatile("" ::: "memory");                                             \
    __builtin_amdgcn_s_barrier();                                              \
    asm volatile("" ::: "memory");                                             \
} while (0)

    floatx4 acc[8][4];
#pragma unroll
    for (int mi = 0; mi < 8; ++mi)
#pragma unroll
        for (int ni = 0; ni < 4; ++ni)
            acc[mi][ni] = (floatx4){0.f, 0.f, 0.f, 0.f};

    bf16x8 bfr[4][2];

    // prologue: buf0 full (kt0) + buf1.B (kt1); wait buf0, leave buf1.B in flight
    STAGE_HALF(0,             pAs);
    STAGE_HALF(8192,          pAs + 128 * DIM);
    STAGE_HALF(16384,         pBs);
    STAGE_HALF(16384 + 8192,  pBs + 128 * DIM);
    STAGE_HALF(49152,         pBs + 64);
    STAGE_HALF(49152 + 8192,  pBs + 128 * DIM + 64);
    asm volatile("s_waitcnt vmcnt(4)" ::: "memory");
    __builtin_amdgcn_s_barrier();
    asm volatile("" ::: "memory");

    for (int it = 0; it < 4; ++it) {
        const unsigned short* pA1 = pAs + (size_t)(2 * it + 1) * 64;
        const unsigned short* pB2 = pBs + (size_t)(2 * it + 2) * 64;
        const unsigned short* pA2 = pAs + (size_t)(2 * it + 2) * 64;
        const unsigned short* pB3 = pBs + (size_t)(2 * it + 3) * 64;

        // ---- K-tile 2*it from buf0 ----
        PHASE(0, 0, LOADB(16384), { STAGE_HALF(32768, pA1); });
        PHASE(0, 2, ((void)0),    { STAGE_HALF(32768 + 8192, pA1 + 128 * DIM); });
        PHASE(0, 4, ((void)0),    { if (it < 3) STAGE_HALF(16384, pB2); });
        PHASE(0, 6, ((void)0), {
            if (it < 3) {
                STAGE_HALF(16384 + 8192, pB2 + 128 * DIM);
                asm volatile("s_waitcnt vmcnt(4)" ::: "memory");
            } else {
                asm volatile("s_waitcnt vmcnt(0)" ::: "memory");
            }
        });
        // ---- K-tile 2*it+1 from buf1 ----
        PHASE(32768, 0, LOADB(49152), { if (it < 3) STAGE_HALF(0, pA2); });
        PHASE(32768, 2, ((void)0),    { if (it < 3) STAGE_HALF(8192, pA2 + 128 * DIM); });
        PHASE(32768, 4, ((void)0),    { if (it < 3) STAGE_HALF(49152, pB3); });
        PHASE(32768, 6, ((void)0), {
            if (it < 3) {
                STAGE_HALF(49152 + 8192, pB3 + 128 * DIM);
                asm volatile("s_waitcnt vmcnt(4)" ::: "memory");
            }
        });
    }
#undef PHASE
#undef LOADB
#undef STAGE_HALF

    __syncthreads();

    // ---- Epilogue: pv = sum_e p*(0.5g+l), pg = sum_e (g+l)^2 over this et ----
    float lcv[4];
#pragma unroll
    for (int ni = 0; ni < 4; ++ni)
        lcv[ni] = l_coefs[(et * 256 + wn * 64 + ni * 16 + c) * NQ + k];

    const unsigned short* Pe = Pb + (size_t)(m0 + wm * 128) * DIM + et * 256 + wn * 64 + c;
    float* red = (float*)smem;   // reuse LDS: 8 waves x 128 rows x {pv,pg} = 8 KB

#pragma unroll
    for (int mi = 0; mi < 8; ++mi)
#pragma unroll
        for (int r = 0; r < 4; ++r) {
            const unsigned short* Prow = Pe + (size_t)(mi * 16 + quad * 4 + r) * DIM;
            float pv = 0.f, pg = 0.f;
#pragma unroll
            for (int ni = 0; ni < 4; ++ni) {
                const float g = acc[mi][ni][r];
                const float l = lcv[ni];
                pv += bf2f(Prow[ni * 16]) * (0.5f * g + l);
                const float gq = g + l;
                pg += gq * gq;
            }
#pragma unroll
            for (int off = 1; off < 16; off <<= 1) {
                pv += __shfl_xor(pv, off);
                pg += __shfl_xor(pg, off);
            }
            if (c == 0) {
                const int row16 = mi * 16 + quad * 4 + r;
                red[(w * 128 + row16) * 2 + 0] = pv;
                red[(w * 128 + row16) * 2 + 1] = pg;
            }
        }
    __syncthreads();

    if (tid < 256) {
        const int row16 = tid & 127;
        const int wmf   = tid >> 7;
        float pv = 0.f, pg = 0.f;
#pragma unroll
        for (int wnf = 0; wnf < 4; ++wnf) {
            const int wi = wmf * 4 + wnf;
            pv += red[(wi * 128 + row16) * 2 + 0];
            pg += red[(wi * 128 + row16) * 2 + 1];
        }
        part[((size_t)(et * NQ + k)) * BATCH + m0 + wmf * 128 + row16] =
            make_float2(pv, pg);
    }
}

// Final: block per k. Reduces npart[k][*] -> norm2 in-block, then combines the
// 2 e-range partials into scores (coalesced reads).
__global__ void hsq_final_kernel(const float2* __restrict__ part,
                                 const float* __restrict__ npart,
                                 const float* __restrict__ free_coefs,
                                 float* __restrict__ out) {
    const int k = blockIdx.x;
    const int t = threadIdx.x;
    __shared__ float ws[4];

    const float4* src = (const float4*)(npart + (size_t)k * 2048);
    const float4 a = src[t * 2], b = src[t * 2 + 1];
    float s = a.x + a.y + a.z + a.w + b.x + b.y + b.z + b.w;
#pragma unroll
    for (int off = 1; off < 64; off <<= 1) s += __shfl_xor(s, off);
    if ((t & 63) == 0) ws[t >> 6] = s;
    __syncthreads();
    const float nrm = sqrtf(ws[0] + ws[1] + ws[2] + ws[3]);
    const float fc  = free_coefs[k];

#pragma unroll
    for (int i = 0; i < 8; ++i) {
        const int bidx = i * 256 + t;
        float pv = 0.f, pg = 0.f;
#pragma unroll
        for (int eb = 0; eb < 2; ++eb) {
            const float2 p = part[((size_t)(eb * NQ + k)) * BATCH + bidx];
            pv += p.x; pg += p.y;
        }
        const float vals = fabsf(pv + fc);
        out[(size_t)bidx * NQ + k] = (sqrtf(0.25f * pg + vals * nrm) - 0.5f * sqrtf(pg)) / nrm;
    }
}

extern "C" void kernel_launch(void* const* d_in, const int* in_sizes, int n_in,
                              void* d_out, int out_size, void* d_ws, size_t ws_size,
                              hipStream_t stream) {
    const float* points     = (const float*)d_in[0];  // (2048, 512)
    const float* q_coefs    = (const float*)d_in[1];  // (131328, 64)
    const float* l_coefs    = (const float*)d_in[2];  // (512, 64)
    const float* free_coefs = (const float*)d_in[3];  // (1, 64)
    float* out = (float*)d_out;                       // (2048, 64)

    char* ws = (char*)d_ws;
    unsigned short* W  = (unsigned short*)ws;                              // 32 MiB
    unsigned short* Pb = (unsigned short*)(ws + 33554432);                 // 2 MiB
    float2*         part  = (float2*)(ws + 35651584);                      // 2 MiB
    float*          npart = (float*)(ws + 37748736);                       // 512 KiB

    // 128 KiB dynamic LDS needs the opt-in (one-time; not a stream op, safe
    // under graph capture).
    static bool attr_done = false;
    if (!attr_done) {
        (void)hipFuncSetAttribute((const void*)hsq_gemm_kernel,
                                  hipFuncAttributeMaxDynamicSharedMemorySize,
                                  131072);
        attr_done = true;
    }

    hsq_expand_kernel<<<dim3(512, 5), 512, 0, stream>>>(q_coefs, points, W, Pb, npart);
    hsq_gemm_kernel<<<dim3(1024), dim3(512), 131072, stream>>>(Pb, W, l_coefs, part);
    hsq_final_kernel<<<dim3(NQ), 256, 0, stream>>>(part, npart, free_coefs, out);
}